// Round 5
// baseline (184.476 us; speedup 1.0000x reference)
//
#include <hip/hip_runtime.h>
#include <math.h>

// Problem constants (fixed by setup_inputs)
#define D 1024
#define B 32
#define N 1024          // patches per image (32x32)
#define SIDE 32
#define OUT 512
#define NLAYER 4
#define TAU_INV (1.0f/0.07f)
#define EPS_NORM 1e-12f

__device__ __forceinline__ float wave_sum(float s) {
#pragma unroll
    for (int m = 32; m; m >>= 1) s += __shfl_xor(s, m);
    return s;
}

// ---------------------------------------------------------------------------
// Kernel 0: per-layer combined seg weight row:
//   what[l][:] = (w0/||w0|| - w1/||w1||) / tau
// so seg logit-diff = (x . what) / ||x||. 4 blocks x 64 threads.
// ---------------------------------------------------------------------------
__global__ void prep_kernel(const float* w0, const float* w1,
                            const float* w2, const float* w3,
                            float* what) {
    int l = blockIdx.x;
    const float* w = (l == 0) ? w0 : (l == 1) ? w1 : (l == 2) ? w2 : w3;
    int lane = threadIdx.x;

    float4 wa[4], wb[4];
    float s00 = 0.f, s11 = 0.f;
#pragma unroll
    for (int kk = 0; kk < 4; ++kk) {
        int off = kk * 256 + lane * 4;
        wa[kk] = *reinterpret_cast<const float4*>(w + off);
        wb[kk] = *reinterpret_cast<const float4*>(w + D + off);
        s00 += wa[kk].x * wa[kk].x + wa[kk].y * wa[kk].y + wa[kk].z * wa[kk].z + wa[kk].w * wa[kk].w;
        s11 += wb[kk].x * wb[kk].x + wb[kk].y * wb[kk].y + wb[kk].z * wb[kk].z + wb[kk].w * wb[kk].w;
    }
    s00 = wave_sum(s00); s11 = wave_sum(s11);
    float iw0 = TAU_INV / fmaxf(sqrtf(s00), EPS_NORM);
    float iw1 = TAU_INV / fmaxf(sqrtf(s11), EPS_NORM);
    float* o = what + (size_t)l * D;
#pragma unroll
    for (int kk = 0; kk < 4; ++kk) {
        int off = kk * 256 + lane * 4;
        float4 r;
        r.x = wa[kk].x * iw0 - wb[kk].x * iw1;
        r.y = wa[kk].y * iw0 - wb[kk].y * iw1;
        r.z = wa[kk].z * iw0 - wb[kk].z * iw1;
        r.w = wa[kk].w * iw0 - wb[kk].w * iw1;
        *reinterpret_cast<float4*>(o + off) = r;
    }
}

// ---------------------------------------------------------------------------
// Kernel 1: cls logits (computes its own w_cls norms). Unchanged (~3 us).
// ---------------------------------------------------------------------------
__global__ void cls_kernel(const float* c0, const float* wc0,
                           const float* c1, const float* wc1,
                           const float* c2, const float* wc2,
                           const float* c3, const float* wc3,
                           float* out) {
    int wid = blockIdx.x * 4 + (threadIdx.x >> 6);   // 0..127
    int lane = threadIdx.x & 63;
    int l = wid >> 5;
    int b = wid & 31;
    const float* cls; const float* wc;
    if      (l == 0) { cls = c0; wc = wc0; }
    else if (l == 1) { cls = c1; wc = wc1; }
    else if (l == 2) { cls = c2; wc = wc2; }
    else             { cls = c3; wc = wc3; }
    const float* x = cls + (size_t)b * D;

    float sxx = 0.f, sx0 = 0.f, sx1 = 0.f, s00 = 0.f, s11 = 0.f;
#pragma unroll
    for (int kk = 0; kk < 4; ++kk) {
        int off = kk * 256 + lane * 4;
        const float4 v  = *reinterpret_cast<const float4*>(x + off);
        const float4 a  = *reinterpret_cast<const float4*>(wc + off);
        const float4 bb = *reinterpret_cast<const float4*>(wc + D + off);
        sxx += v.x * v.x + v.y * v.y + v.z * v.z + v.w * v.w;
        sx0 += v.x * a.x + v.y * a.y + v.z * a.z + v.w * a.w;
        sx1 += v.x * bb.x + v.y * bb.y + v.z * bb.z + v.w * bb.w;
        s00 += a.x * a.x + a.y * a.y + a.z * a.z + a.w * a.w;
        s11 += bb.x * bb.x + bb.y * bb.y + bb.z * bb.z + bb.w * bb.w;
    }
    sxx = wave_sum(sxx); sx0 = wave_sum(sx0); sx1 = wave_sum(sx1);
    s00 = wave_sum(s00); s11 = wave_sum(s11);
    if (lane == 0) {
        float invx = 1.0f / fmaxf(sqrtf(sxx), EPS_NORM);
        float iw0  = 1.0f / fmaxf(sqrtf(s00), EPS_NORM);
        float iw1  = 1.0f / fmaxf(sqrtf(s11), EPS_NORM);
        out[((size_t)l * B + b) * 2 + 0] = sx0 * invx * iw0 * TAU_INV;
        out[((size_t)l * B + b) * 2 + 1] = sx1 * invx * iw1 * TAU_INV;
    }
}

// ---------------------------------------------------------------------------
// Kernel 2: seg probabilities, restructured for latency (R4 post-mortem:
// 153 us @ 1.8 TB/s, serial 6-level shfl chains x3 per row were the stall).
//  - 16-lane groups: lanes (g=lane>>4, sub=lane&15); group g owns one row.
//    One 4-level reduce covers 4 rows at once: 2 ds-ops/row vs 18.
//  - Only 2 dots per row (x.x and x.what) thanks to the precombined weight.
//  - 8 rows per wave (2 quad-batches); what row held in 16 float4 regs.
// waves = 131072/8 = 16384 -> 4096 blocks x 256.
// ---------------------------------------------------------------------------
__global__ __launch_bounds__(256) void seg_kernel(
        const float* p0, const float* p1, const float* p2, const float* p3,
        const float* what, float* probs) {
    int wid  = blockIdx.x * 4 + (threadIdx.x >> 6);  // 0..16383
    int lane = threadIdx.x & 63;
    int grp  = lane >> 4;        // row within quad
    int sub  = lane & 15;        // position within row
    int base = wid * 8;          // first global row (multiple of 8)
    int l    = base >> 15;       // 32768 rows per layer
    int rem  = base & 32767;     // layer-local row index
    const float* patch = (l == 0) ? p0 : (l == 1) ? p1 : (l == 2) ? p2 : p3;

    // Preload this lane's 64 floats of the combined weight row (L2-hot).
    const float* wrow = what + (size_t)l * D + sub * 4;
    float4 wv[16];
#pragma unroll
    for (int kk = 0; kk < 16; ++kk)
        wv[kk] = *reinterpret_cast<const float4*>(wrow + kk * 64);

#pragma unroll
    for (int half = 0; half < 2; ++half) {
        int row = rem + half * 4 + grp;              // this group's row
        const float* x = patch + (size_t)row * D + sub * 4;
        float sxx = 0.f, sd = 0.f;
#pragma unroll
        for (int kk = 0; kk < 16; ++kk) {
            const float4 v = *reinterpret_cast<const float4*>(x + kk * 64);
            sxx += v.x * v.x + v.y * v.y + v.z * v.z + v.w * v.w;
            sd  += v.x * wv[kk].x + v.y * wv[kk].y + v.z * wv[kk].z + v.w * wv[kk].w;
        }
        // reduce within the 16-lane group (4 levels, 2 sums, covers 4 rows)
#pragma unroll
        for (int m = 1; m < 16; m <<= 1) {
            sxx += __shfl_xor(sxx, m);
            sd  += __shfl_xor(sd, m);
        }
        if (sub == 0) {
            float invx = 1.0f / fmaxf(sqrtf(sxx), EPS_NORM);
            float diff = sd * invx;                  // l0 - l1 (tau folded in)
            float pr0 = 1.0f / (1.0f + __expf(-diff));
            float pr1 = 1.0f / (1.0f + __expf(diff));
            int b = row >> 10, n = row & 1023;
            float* o = probs + ((size_t)(l * B + b) * 2) * N;
            o[n]     = pr0;   // 4 lanes write consecutive n -> coalesced 16B
            o[N + n] = pr1;
        }
    }
}

// ---------------------------------------------------------------------------
// Kernel 3: bilinear 16x upsample 32x32 -> 512x512 per image. (~25 us)
// ---------------------------------------------------------------------------
__global__ __launch_bounds__(256) void upsample_kernel(const float* probs, float* out) {
    __shared__ float rowbuf[64 * 32];

    int img   = blockIdx.x >> 3;     // 0..255
    int chunk = blockIdx.x & 7;      // 0..7 (64 output rows each)
    const float* S = probs + (size_t)img * (SIDE * SIDE);

    for (int e = threadIdx.x; e < 64 * 32; e += 256) {
        int r = e >> 5;
        int xs = e & 31;
        int gy = chunk * 64 + r;
        float fy = fmaxf(((float)gy + 0.5f) * 0.0625f - 0.5f, 0.0f);
        int y0 = min((int)fy, SIDE - 1);
        int y1 = min(y0 + 1, SIDE - 1);
        float wy = fy - (float)y0;
        float a = S[y0 * SIDE + xs];
        float b = S[y1 * SIDE + xs];
        rowbuf[e] = a + wy * (b - a);
    }
    __syncthreads();

    int tid = threadIdx.x;
    int xv  = tid & 127;             // float4 column, fixed across iterations
    int rhalf = tid >> 7;            // 0/1
    float fx0 = fmaxf(((float)(4 * xv) + 0.5f) * 0.0625f - 0.5f, 0.0f);
    int x0 = min((int)fx0, SIDE - 1);
    int x1 = min(x0 + 1, SIDE - 1);
    float wx[4];
#pragma unroll
    for (int j = 0; j < 4; ++j) {
        float fx = fmaxf(((float)(4 * xv + j) + 0.5f) * 0.0625f - 0.5f, 0.0f);
        wx[j] = fx - (float)x0;
    }

    float4* obase = reinterpret_cast<float4*>(out) + (size_t)img * (OUT * OUT / 4);
#pragma unroll 8
    for (int it = 0; it < 32; ++it) {
        int r = it * 2 + rhalf;
        const float* rb = rowbuf + r * 32;
        float r0 = rb[x0];
        float d  = rb[x1] - r0;
        float4 o;
        o.x = r0 + wx[0] * d;
        o.y = r0 + wx[1] * d;
        o.z = r0 + wx[2] * d;
        o.w = r0 + wx[3] * d;
        int gy = chunk * 64 + r;
        obase[(size_t)gy * (OUT / 4) + xv] = o;
    }
}

// ---------------------------------------------------------------------------
extern "C" void kernel_launch(void* const* d_in, const int* in_sizes, int n_in,
                              void* d_out, int out_size, void* d_ws, size_t ws_size,
                              hipStream_t stream) {
    const float* cls[4];  const float* patch[4];
    const float* wcls[4]; const float* wseg[4];
    for (int l = 0; l < 4; ++l) {
        cls[l]   = (const float*)d_in[4 * l + 0];
        patch[l] = (const float*)d_in[4 * l + 1];
        wcls[l]  = (const float*)d_in[4 * l + 2];
        wseg[l]  = (const float*)d_in[4 * l + 3];
    }
    float* out = (float*)d_out;            // [4,32,2] cls logits then [4,32,2,512,512]
    float* seg_out = out + NLAYER * B * 2; // offset 256 floats

    float* ws_what  = (float*)d_ws;        // [4][1024] combined weights (16 KB)
    float* ws_probs = ws_what + NLAYER * D;// [4][32][2][1024] = 1 MB

    prep_kernel<<<4, 64, 0, stream>>>(wseg[0], wseg[1], wseg[2], wseg[3], ws_what);

    cls_kernel<<<32, 256, 0, stream>>>(cls[0], wcls[0], cls[1], wcls[1],
                                       cls[2], wcls[2], cls[3], wcls[3], out);

    seg_kernel<<<4096, 256, 0, stream>>>(patch[0], patch[1], patch[2], patch[3],
                                         ws_what, ws_probs);

    upsample_kernel<<<2048, 256, 0, stream>>>(ws_probs, seg_out);
}

// Round 6
// 183.194 us; speedup vs baseline: 1.0070x; 1.0070x over previous
//
#include <hip/hip_runtime.h>
#include <math.h>

// Problem constants (fixed by setup_inputs)
#define D 1024
#define B 32
#define N 1024          // patches per image (32x32)
#define SIDE 32
#define OUT 512
#define NLAYER 4
#define TAU_INV (1.0f/0.07f)
#define EPS_NORM 1e-12f

__device__ __forceinline__ float wave_sum(float s) {
#pragma unroll
    for (int m = 32; m; m >>= 1) s += __shfl_xor(s, m);
    return s;
}

// ---------------------------------------------------------------------------
// Kernel 0: per-layer combined seg weight row:
//   what[l][:] = (w0/||w0|| - w1/||w1||) / tau
// so seg logit-diff = (x . what) / ||x||. 4 blocks x 64 threads.
// ---------------------------------------------------------------------------
__global__ void prep_kernel(const float* w0, const float* w1,
                            const float* w2, const float* w3,
                            float* what) {
    int l = blockIdx.x;
    const float* w = (l == 0) ? w0 : (l == 1) ? w1 : (l == 2) ? w2 : w3;
    int lane = threadIdx.x;

    float4 wa[4], wb[4];
    float s00 = 0.f, s11 = 0.f;
#pragma unroll
    for (int kk = 0; kk < 4; ++kk) {
        int off = kk * 256 + lane * 4;
        wa[kk] = *reinterpret_cast<const float4*>(w + off);
        wb[kk] = *reinterpret_cast<const float4*>(w + D + off);
        s00 += wa[kk].x * wa[kk].x + wa[kk].y * wa[kk].y + wa[kk].z * wa[kk].z + wa[kk].w * wa[kk].w;
        s11 += wb[kk].x * wb[kk].x + wb[kk].y * wb[kk].y + wb[kk].z * wb[kk].z + wb[kk].w * wb[kk].w;
    }
    s00 = wave_sum(s00); s11 = wave_sum(s11);
    float iw0 = TAU_INV / fmaxf(sqrtf(s00), EPS_NORM);
    float iw1 = TAU_INV / fmaxf(sqrtf(s11), EPS_NORM);
    float* o = what + (size_t)l * D;
#pragma unroll
    for (int kk = 0; kk < 4; ++kk) {
        int off = kk * 256 + lane * 4;
        float4 r;
        r.x = wa[kk].x * iw0 - wb[kk].x * iw1;
        r.y = wa[kk].y * iw0 - wb[kk].y * iw1;
        r.z = wa[kk].z * iw0 - wb[kk].z * iw1;
        r.w = wa[kk].w * iw0 - wb[kk].w * iw1;
        *reinterpret_cast<float4*>(o + off) = r;
    }
}

// ---------------------------------------------------------------------------
// Kernel 1: cls logits (computes its own w_cls norms). ~3 us, unchanged.
// ---------------------------------------------------------------------------
__global__ void cls_kernel(const float* c0, const float* wc0,
                           const float* c1, const float* wc1,
                           const float* c2, const float* wc2,
                           const float* c3, const float* wc3,
                           float* out) {
    int wid = blockIdx.x * 4 + (threadIdx.x >> 6);   // 0..127
    int lane = threadIdx.x & 63;
    int l = wid >> 5;
    int b = wid & 31;
    const float* cls; const float* wc;
    if      (l == 0) { cls = c0; wc = wc0; }
    else if (l == 1) { cls = c1; wc = wc1; }
    else if (l == 2) { cls = c2; wc = wc2; }
    else             { cls = c3; wc = wc3; }
    const float* x = cls + (size_t)b * D;

    float sxx = 0.f, sx0 = 0.f, sx1 = 0.f, s00 = 0.f, s11 = 0.f;
#pragma unroll
    for (int kk = 0; kk < 4; ++kk) {
        int off = kk * 256 + lane * 4;
        const float4 v  = *reinterpret_cast<const float4*>(x + off);
        const float4 a  = *reinterpret_cast<const float4*>(wc + off);
        const float4 bb = *reinterpret_cast<const float4*>(wc + D + off);
        sxx += v.x * v.x + v.y * v.y + v.z * v.z + v.w * v.w;
        sx0 += v.x * a.x + v.y * a.y + v.z * a.z + v.w * a.w;
        sx1 += v.x * bb.x + v.y * bb.y + v.z * bb.z + v.w * bb.w;
        s00 += a.x * a.x + a.y * a.y + a.z * a.z + a.w * a.w;
        s11 += bb.x * bb.x + bb.y * bb.y + bb.z * bb.z + bb.w * bb.w;
    }
    sxx = wave_sum(sxx); sx0 = wave_sum(sx0); sx1 = wave_sum(sx1);
    s00 = wave_sum(s00); s11 = wave_sum(s11);
    if (lane == 0) {
        float invx = 1.0f / fmaxf(sqrtf(sxx), EPS_NORM);
        float iw0  = 1.0f / fmaxf(sqrtf(s00), EPS_NORM);
        float iw1  = 1.0f / fmaxf(sqrtf(s11), EPS_NORM);
        out[((size_t)l * B + b) * 2 + 0] = sx0 * invx * iw0 * TAU_INV;
        out[((size_t)l * B + b) * 2 + 1] = sx1 * invx * iw1 * TAU_INV;
    }
}

// ---------------------------------------------------------------------------
// Kernel 2: seg probabilities.
// R5 post-mortem: wv[16] ate 64 of 68 VGPRs -> no registers for in-flight
// loads -> latency-bound at 1.75 TB/s. Redesign for MLP:
//  - 64-lane rows, combined weight = only wv[4] (16 VGPRs).
//  - 8 rows/wave as 4 pairs; both rows of a pair fully loaded (8 float4,
//    32 VGPRs in flight) before FMAs; unrolled so next pair's loads overlap
//    the current pair's shfl-reduce.
//  - All lanes compute sigmoid (no divergence); lane 0 stores 4x float4.
// waves = 131072/8 = 16384 -> 4096 blocks x 256.
// ---------------------------------------------------------------------------
__global__ __launch_bounds__(256) void seg_kernel(
        const float* p0, const float* p1, const float* p2, const float* p3,
        const float* what, float* probs) {
    int wid  = blockIdx.x * 4 + (threadIdx.x >> 6);  // 0..16383
    int lane = threadIdx.x & 63;
    int base = wid * 8;          // first global row (multiple of 8)
    int l    = base >> 15;       // 32768 rows per layer
    int rem  = base & 32767;     // layer-local row index
    const float* patch = (l == 0) ? p0 : (l == 1) ? p1 : (l == 2) ? p2 : p3;

    // Combined weight: this lane's 16 floats (16 VGPRs only).
    const float* wbase = what + (size_t)l * D + lane * 4;
    float4 wv[4];
#pragma unroll
    for (int kk = 0; kk < 4; ++kk)
        wv[kk] = *reinterpret_cast<const float4*>(wbase + kk * 256);

    const float* xb = patch + (size_t)rem * D + lane * 4;
    float pr0a[8], pr1a[8];
#pragma unroll
    for (int pair = 0; pair < 4; ++pair) {
        const float* xa = xb + (size_t)(pair * 2) * D;
        const float* xc = xa + D;
        // Issue all 8 loads of the pair up front (32 VGPRs in flight).
        float4 va[4], vb[4];
#pragma unroll
        for (int kk = 0; kk < 4; ++kk) va[kk] = *reinterpret_cast<const float4*>(xa + kk * 256);
#pragma unroll
        for (int kk = 0; kk < 4; ++kk) vb[kk] = *reinterpret_cast<const float4*>(xc + kk * 256);

        float sxxA = 0.f, sdA = 0.f, sxxB = 0.f, sdB = 0.f;
#pragma unroll
        for (int kk = 0; kk < 4; ++kk) {
            sxxA += va[kk].x * va[kk].x + va[kk].y * va[kk].y + va[kk].z * va[kk].z + va[kk].w * va[kk].w;
            sdA  += va[kk].x * wv[kk].x + va[kk].y * wv[kk].y + va[kk].z * wv[kk].z + va[kk].w * wv[kk].w;
            sxxB += vb[kk].x * vb[kk].x + vb[kk].y * vb[kk].y + vb[kk].z * vb[kk].z + vb[kk].w * vb[kk].w;
            sdB  += vb[kk].x * wv[kk].x + vb[kk].y * wv[kk].y + vb[kk].z * wv[kk].z + vb[kk].w * wv[kk].w;
        }
#pragma unroll
        for (int m = 32; m; m >>= 1) {
            sxxA += __shfl_xor(sxxA, m);
            sdA  += __shfl_xor(sdA, m);
            sxxB += __shfl_xor(sxxB, m);
            sdB  += __shfl_xor(sdB, m);
        }
        float dA = sdA / fmaxf(sqrtf(sxxA), EPS_NORM);   // l0-l1, tau folded in
        float dB = sdB / fmaxf(sqrtf(sxxB), EPS_NORM);
        pr0a[pair * 2 + 0] = 1.0f / (1.0f + __expf(-dA));
        pr1a[pair * 2 + 0] = 1.0f / (1.0f + __expf(dA));
        pr0a[pair * 2 + 1] = 1.0f / (1.0f + __expf(-dB));
        pr1a[pair * 2 + 1] = 1.0f / (1.0f + __expf(dB));
    }

    if (lane == 0) {
        int b = rem >> 10, n0 = rem & 1023;   // rows rem..rem+7 stay in one image
        float* o = probs + ((size_t)(l * B + b) * 2) * N;
        float4* o0 = reinterpret_cast<float4*>(o + n0);
        float4* o1 = reinterpret_cast<float4*>(o + N + n0);
        o0[0] = make_float4(pr0a[0], pr0a[1], pr0a[2], pr0a[3]);
        o0[1] = make_float4(pr0a[4], pr0a[5], pr0a[6], pr0a[7]);
        o1[0] = make_float4(pr1a[0], pr1a[1], pr1a[2], pr1a[3]);
        o1[1] = make_float4(pr1a[4], pr1a[5], pr1a[6], pr1a[7]);
    }
}

// ---------------------------------------------------------------------------
// Kernel 3: bilinear 16x upsample 32x32 -> 512x512 per image. (~25 us)
// ---------------------------------------------------------------------------
__global__ __launch_bounds__(256) void upsample_kernel(const float* probs, float* out) {
    __shared__ float rowbuf[64 * 32];

    int img   = blockIdx.x >> 3;     // 0..255
    int chunk = blockIdx.x & 7;      // 0..7 (64 output rows each)
    const float* S = probs + (size_t)img * (SIDE * SIDE);

    for (int e = threadIdx.x; e < 64 * 32; e += 256) {
        int r = e >> 5;
        int xs = e & 31;
        int gy = chunk * 64 + r;
        float fy = fmaxf(((float)gy + 0.5f) * 0.0625f - 0.5f, 0.0f);
        int y0 = min((int)fy, SIDE - 1);
        int y1 = min(y0 + 1, SIDE - 1);
        float wy = fy - (float)y0;
        float a = S[y0 * SIDE + xs];
        float b = S[y1 * SIDE + xs];
        rowbuf[e] = a + wy * (b - a);
    }
    __syncthreads();

    int tid = threadIdx.x;
    int xv  = tid & 127;             // float4 column, fixed across iterations
    int rhalf = tid >> 7;            // 0/1
    float fx0 = fmaxf(((float)(4 * xv) + 0.5f) * 0.0625f - 0.5f, 0.0f);
    int x0 = min((int)fx0, SIDE - 1);
    int x1 = min(x0 + 1, SIDE - 1);
    float wx[4];
#pragma unroll
    for (int j = 0; j < 4; ++j) {
        float fx = fmaxf(((float)(4 * xv + j) + 0.5f) * 0.0625f - 0.5f, 0.0f);
        wx[j] = fx - (float)x0;
    }

    float4* obase = reinterpret_cast<float4*>(out) + (size_t)img * (OUT * OUT / 4);
#pragma unroll 8
    for (int it = 0; it < 32; ++it) {
        int r = it * 2 + rhalf;
        const float* rb = rowbuf + r * 32;
        float r0 = rb[x0];
        float d  = rb[x1] - r0;
        float4 o;
        o.x = r0 + wx[0] * d;
        o.y = r0 + wx[1] * d;
        o.z = r0 + wx[2] * d;
        o.w = r0 + wx[3] * d;
        int gy = chunk * 64 + r;
        obase[(size_t)gy * (OUT / 4) + xv] = o;
    }
}

// ---------------------------------------------------------------------------
extern "C" void kernel_launch(void* const* d_in, const int* in_sizes, int n_in,
                              void* d_out, int out_size, void* d_ws, size_t ws_size,
                              hipStream_t stream) {
    const float* cls[4];  const float* patch[4];
    const float* wcls[4]; const float* wseg[4];
    for (int l = 0; l < 4; ++l) {
        cls[l]   = (const float*)d_in[4 * l + 0];
        patch[l] = (const float*)d_in[4 * l + 1];
        wcls[l]  = (const float*)d_in[4 * l + 2];
        wseg[l]  = (const float*)d_in[4 * l + 3];
    }
    float* out = (float*)d_out;            // [4,32,2] cls logits then [4,32,2,512,512]
    float* seg_out = out + NLAYER * B * 2; // offset 256 floats

    float* ws_what  = (float*)d_ws;        // [4][1024] combined weights (16 KB)
    float* ws_probs = ws_what + NLAYER * D;// [4][32][2][1024] = 1 MB

    prep_kernel<<<4, 64, 0, stream>>>(wseg[0], wseg[1], wseg[2], wseg[3], ws_what);

    cls_kernel<<<32, 256, 0, stream>>>(cls[0], wcls[0], cls[1], wcls[1],
                                       cls[2], wcls[2], cls[3], wcls[3], out);

    seg_kernel<<<4096, 256, 0, stream>>>(patch[0], patch[1], patch[2], patch[3],
                                         ws_what, ws_probs);

    upsample_kernel<<<2048, 256, 0, stream>>>(ws_probs, seg_out);
}